// Round 7
// baseline (106.017 us; speedup 1.0000x reference)
//
#include <hip/hip_runtime.h>
#include <hip/hip_bf16.h>
#include <cstdint>

#define N_ROWS 4096
#define N_CLS  8192
#define D_EMB  512
#define K_DIM  1024   // bytes per row: [x^2 s-channel 512][2x ps-channel 512]

using f32x4 = __attribute__((ext_vector_type(4))) float;

__device__ __forceinline__ float softplus_f(float v) {
  return (v > 20.f) ? v : log1pf(expf(v));
}

// pack 2 f32 -> 2 fp8 e4m3 (OCP, RNE) in low 16 bits
__device__ __forceinline__ unsigned short pack2_e4m3(float a, float b) {
  return (unsigned short)(__builtin_amdgcn_cvt_pk_fp8_f32(a, b, 0, false) & 0xffff);
}

__device__ __forceinline__ float e4m3_to_f(unsigned char v) {
  int e = (v >> 3) & 15, m = v & 7;
  float f;
  if (e) f = __uint_as_float((unsigned int)((e + 120) << 23) | ((unsigned int)m << 20));
  else   f = (float)m * 0.001953125f;   // m * 2^-9
  return (v & 0x80) ? -f : f;
}

// block-wide sum for 256 threads (4 waves); re-entrant (syncs guard the LDS)
__device__ __forceinline__ float block_sum256(float v) {
  __shared__ float red[4];
  #pragma unroll
  for (int o = 32; o; o >>= 1) v += __shfl_xor(v, o);
  __syncthreads();
  if ((threadIdx.x & 63) == 0) red[threadIdx.x >> 6] = v;
  __syncthreads();
  return red[0] + red[1] + red[2] + red[3];
}

__device__ __forceinline__ void global_to_lds16(const void* g, void* l) {
  const __attribute__((address_space(1))) unsigned int* gp =
      reinterpret_cast<const __attribute__((address_space(1))) unsigned int*>(
          reinterpret_cast<uintptr_t>(g));
  __attribute__((address_space(3))) unsigned int* lp =
      reinterpret_cast<__attribute__((address_space(3))) unsigned int*>(
          reinterpret_cast<uintptr_t>(l));
  __builtin_amdgcn_global_load_lds(gp, lp, 16, 0, 0);
}

// ---------------------------------------------------------------------------
// K1: fused prep. Blocks [0, N_CLS): per-class -> Bmat fp8 [s | P*s], tvec,
//     klc. Blocks [N_CLS, N_CLS+N_ROWS): per-row -> Amat fp8 [-Xn^2 | 2Xn].
// ---------------------------------------------------------------------------
__global__ __launch_bounds__(256) void k_prep(const float* __restrict__ proxies,
                                              const float* __restrict__ sigmas_inv,
                                              const float* __restrict__ X,
                                              unsigned char* __restrict__ Bmat,
                                              unsigned char* __restrict__ Amat,
                                              float* __restrict__ tvec,
                                              float* __restrict__ klc) {
  const int bid = blockIdx.x;
  const int tid = threadIdx.x;
  if (bid < N_CLS) {
    const int c = bid;
    const float* p  = proxies    + (size_t)c * D_EMB;
    const float* si = sigmas_inv + (size_t)c * D_EMB;
    float2 p2 = ((const float2*)p)[tid];
    float ss = block_sum256(p2.x * p2.x + p2.y * p2.y);
    float invn = 1.0f / fmaxf(sqrtf(ss), 1e-12f);
    float2 s2 = ((const float2*)si)[tid];
    float sp0 = softplus_f(s2.x), sp1 = softplus_f(s2.y);
    float s0 = sp0 * sp0, s1 = sp1 * sp1;
    float pn0 = p2.x * invn, pn1 = p2.y * invn;
    float P0 = 3.0f * pn0, P1 = 3.0f * pn1;
    unsigned short* brow = (unsigned short*)(Bmat + (size_t)c * K_DIM);
    brow[tid]       = pack2_e4m3(s0, s1);
    brow[256 + tid] = pack2_e4m3(P0 * s0, P1 * s1);
    float tc = P0 * P0 * s0 + P1 * P1 * s1;
    float kl = 0.5f * (1.0f / s0 + pn0 * pn0 - 1.0f + 2.0f * logf(sp0))
             + 0.5f * (1.0f / s1 + pn1 * pn1 - 1.0f + 2.0f * logf(sp1));
    tc = block_sum256(tc);
    kl = block_sum256(kl);
    if (tid == 0) { tvec[c] = tc; klc[c] = kl; }
  } else {
    const int n = bid - N_CLS;
    const float* x = X + (size_t)n * D_EMB;
    float2 x2 = ((const float2*)x)[tid];
    float ss = block_sum256(x2.x * x2.x + x2.y * x2.y);
    float invn = 3.0f / fmaxf(sqrtf(ss), 1e-12f);   // SCALE folded in
    float v0 = x2.x * invn, v1 = x2.y * invn;
    unsigned short* arow = (unsigned short*)(Amat + (size_t)n * K_DIM);
    arow[tid]       = pack2_e4m3(-v0 * v0, -v1 * v1);
    arow[256 + tid] = pack2_e4m3(2.0f * v0, 2.0f * v1);
  }
}

// ---------------------------------------------------------------------------
// K3: 128x128-tile fp8 MFMA GEMM (K=1024 bytes), 4 waves (2x2, 64x64/wave),
//     2-slot LDS (32 KB -> 5 blocks/CU = 20 waves/CU). Simple proven pipeline:
//     {stage(t+1); compute(t); syncthreads}. XOR swizzle (inverse on global
//     source, applied on LDS read). XCD-chunked block swizzle, rt-fastest so
//     each XCD's A working set (4 MB) fits its private L2. Fused row
//     max/sumexp epilogue -> Pm/Psum[n][64].
// ---------------------------------------------------------------------------
__global__ __launch_bounds__(256, 5) void k_gemm_lse(const unsigned char* __restrict__ Amat,
                                                     const unsigned char* __restrict__ Bmat,
                                                     const float* __restrict__ tvec,
                                                     float* __restrict__ Pm,
                                                     float* __restrict__ Psum) {
  // LDS map: As[2][8192] at 0 ; Bs[2][8192] at 16384 ; total 32768 B.
  // Epilogue ms[128][2][2] (4 KB) overlays As[0]; last compute reads slot 1.
  __shared__ __align__(16) unsigned char lds[32768];
  const int tid  = threadIdx.x;
  const int lane = tid & 63;
  const int wave = tid >> 6;
  const int wr = wave >> 1, wc = wave & 1;          // 2x2 wave grid; 64x64/wave
  // T1: chunked XCD swizzle. nwg=2048, 256 consecutive per XCD; rt fastest.
  const int swz  = ((int)blockIdx.x & 7) * 256 + ((int)blockIdx.x >> 3);
  const int rt   = swz & 31;                        // 32 row tiles (128 rows)
  const int ct   = swz >> 5;                        // 64 col tiles (128 cols)
  const int row0 = rt * 128;
  const int col0 = ct * 128;

  f32x4 acc[4][4];
  #pragma unroll
  for (int i = 0; i < 4; ++i)
    #pragma unroll
    for (int j = 0; j < 4; ++j) acc[i][j] = (f32x4){0.f, 0.f, 0.f, 0.f};

  const int arow = wr * 64 + (lane & 15);           // + mi*16
  const int bcol = wc * 64 + (lane & 15);           // + ni*16
  const int kb8  = (lane >> 4) * 8;                 // k-byte within 32-chunk

  // per-thread staging sources (inverse swizzle on global source address)
  const int f0  = tid * 16;
  const int f1  = 4096 + tid * 16;
  const int sf0 = f0 ^ (((f0 >> 7) & 7) << 4);
  const int sf1 = f1 ^ (((f1 >> 7) & 7) << 4);
  const unsigned char* gA0 = Amat + (size_t)(row0 + (sf0 >> 6)) * K_DIM + (sf0 & 63);
  const unsigned char* gA1 = Amat + (size_t)(row0 + (sf1 >> 6)) * K_DIM + (sf1 & 63);
  const unsigned char* gB0 = Bmat + (size_t)(col0 + (sf0 >> 6)) * K_DIM + (sf0 & 63);
  const unsigned char* gB1 = Bmat + (size_t)(col0 + (sf1 >> 6)) * K_DIM + (sf1 & 63);

  auto stg = [&](int slot, int ko) {                // 4 x 16B loads / thread
    unsigned char* la = lds + slot * 8192;
    unsigned char* lb = lds + 16384 + slot * 8192;
    global_to_lds16(gA0 + ko, la + f0);
    global_to_lds16(gA1 + ko, la + f1);
    global_to_lds16(gB0 + ko, lb + f0);
    global_to_lds16(gB1 + ko, lb + f1);
  };
  auto ld64 = [&](const unsigned char* base, int row, int kb) -> long {
    int f = row * 64 + kb;
    return *(const long*)(base + (f ^ (((f >> 7) & 7) << 4)));
  };

  stg(0, 0);
  __syncthreads();
  for (int t = 0; t < 16; ++t) {
    if (t < 15) stg((t + 1) & 1, (t + 1) * 64);     // issue next-tile loads FIRST
    const unsigned char* Ab = lds + (t & 1) * 8192;
    const unsigned char* Bb = lds + 16384 + (t & 1) * 8192;
    __builtin_amdgcn_s_setprio(1);
    #pragma unroll
    for (int ks = 0; ks < 64; ks += 32) {
      long a[4], b[4];
      #pragma unroll
      for (int mi = 0; mi < 4; ++mi) a[mi] = ld64(Ab, arow + mi * 16, ks + kb8);
      #pragma unroll
      for (int ni = 0; ni < 4; ++ni) b[ni] = ld64(Bb, bcol + ni * 16, ks + kb8);
      #pragma unroll
      for (int mi = 0; mi < 4; ++mi)
        #pragma unroll
        for (int ni = 0; ni < 4; ++ni)
          acc[mi][ni] = __builtin_amdgcn_mfma_f32_16x16x32_fp8_fp8(a[mi], b[ni], acc[mi][ni], 0, 0, 0);
    }
    __builtin_amdgcn_s_setprio(0);
    __syncthreads();   // drains staging vmcnt AFTER compute: latency hidden
  }

  // ---- in-register epilogue: per-row max / sumexp over this wave's 64 cols.
  // C/D layout: col = lane&15, row = (lane>>4)*4 + j.
  float (*ms)[2][2] = (float (*)[2][2])lds;   // overlays As[0]; slot 1 was last read
  float tc[4];
  #pragma unroll
  for (int ni = 0; ni < 4; ++ni)
    tc[ni] = tvec[col0 + wc * 64 + ni * 16 + (lane & 15)];

  #pragma unroll
  for (int mi = 0; mi < 4; ++mi) {
    #pragma unroll
    for (int j = 0; j < 4; ++j) {
      float z0 = acc[mi][0][j] - tc[0];
      float z1 = acc[mi][1][j] - tc[1];
      float z2 = acc[mi][2][j] - tc[2];
      float z3 = acc[mi][3][j] - tc[3];
      float m = fmaxf(fmaxf(z0, z1), fmaxf(z2, z3));
      #pragma unroll
      for (int o = 1; o < 16; o <<= 1) m = fmaxf(m, __shfl_xor(m, o));
      float s = __expf(z0 - m) + __expf(z1 - m) + __expf(z2 - m) + __expf(z3 - m);
      #pragma unroll
      for (int o = 1; o < 16; o <<= 1) s += __shfl_xor(s, o);
      if ((lane & 15) == 0) {
        int rloc = wr * 64 + mi * 16 + ((lane >> 4) << 2) + j;
        ms[rloc][wc][0] = m;
        ms[rloc][wc][1] = s;
      }
    }
  }
  __syncthreads();
  if (tid < 128) {
    float m0 = ms[tid][0][0], s0 = ms[tid][0][1];
    float m1 = ms[tid][1][0], s1 = ms[tid][1][1];
    float M = fmaxf(m0, m1);
    float S = s0 * __expf(m0 - M) + s1 * __expf(m1 - M);
    Pm  [(size_t)(row0 + tid) * 64 + ct] = M;
    Psum[(size_t)(row0 + tid) * 64 + ct] = S;
  }
}

// ---------------------------------------------------------------------------
// K5a: 256-block reduce, target-dot FUSED. Block b:
//      phase 1: rows [b*16, b*16+16): tgt[n] = A[n]·B[T[n]] - t[T[n]]
//               (1 wave per 4 rows, full-wave dot over 1024 fp8)
//      phase 2: same rows -> LSE over 64 partials -> ce partial;
//               classes [b*32, b*32+32) -> kl partial.
// ---------------------------------------------------------------------------
__global__ __launch_bounds__(256) void k_red(const float* __restrict__ Pm,
                                             const float* __restrict__ Psum,
                                             const unsigned char* __restrict__ Amat,
                                             const unsigned char* __restrict__ Bmat,
                                             const float* __restrict__ tvec,
                                             const int* __restrict__ T,
                                             const float* __restrict__ klc,
                                             float* __restrict__ cep,
                                             float* __restrict__ klp) {
  __shared__ float tgt_s[16];
  const int b = blockIdx.x;
  const int tid = threadIdx.x;
  const int lane = tid & 63;
  const int w = tid >> 6;
  // phase 1: target logits for 4 rows per wave
  #pragma unroll
  for (int r = 0; r < 4; ++r) {
    const int loc = w * 4 + r;
    const int n = b * 16 + loc;
    const int c = T[n];
    uint4 av = *(const uint4*)(Amat + (size_t)n * K_DIM + lane * 16);
    uint4 bv = *(const uint4*)(Bmat + (size_t)c * K_DIM + lane * 16);
    const unsigned char* ab = (const unsigned char*)&av;
    const unsigned char* bb = (const unsigned char*)&bv;
    float s = 0.f;
    #pragma unroll
    for (int i = 0; i < 16; ++i) s += e4m3_to_f(ab[i]) * e4m3_to_f(bb[i]);
    #pragma unroll
    for (int o = 32; o; o >>= 1) s += __shfl_xor(s, o);
    if (lane == 0) tgt_s[loc] = s - tvec[c];
  }
  __syncthreads();
  // phase 2: LSE combine (16 lanes/row, 1 float4 each over 64 partials)
  const int loc = tid >> 4;
  const int n = b * 16 + loc;
  const int l4 = tid & 15;
  float4 pm = *(const float4*)(Pm   + (size_t)n * 64 + l4 * 4);
  float4 ps = *(const float4*)(Psum + (size_t)n * 64 + l4 * 4);
  float m = fmaxf(fmaxf(pm.x, pm.y), fmaxf(pm.z, pm.w));
  #pragma unroll
  for (int o = 1; o < 16; o <<= 1) m = fmaxf(m, __shfl_xor(m, o));
  float S = ps.x * __expf(pm.x - m) + ps.y * __expf(pm.y - m)
          + ps.z * __expf(pm.z - m) + ps.w * __expf(pm.w - m);
  #pragma unroll
  for (int o = 1; o < 16; o <<= 1) S += __shfl_xor(S, o);
  float ce = (l4 == 0) ? (m + logf(S) - tgt_s[loc]) : 0.f;
  float kl = (tid < 32) ? klc[b * 32 + tid] : 0.f;
  ce = block_sum256(ce);
  kl = block_sum256(kl);
  if (tid == 0) { cep[b] = ce; klp[b] = kl; }
}

// K5b: final combine (1 block, 256 threads)
__global__ __launch_bounds__(256) void k_fin2(const float* __restrict__ cep,
                                              const float* __restrict__ klp,
                                              float* __restrict__ out) {
  const int tid = threadIdx.x;
  float ce = block_sum256(cep[tid]);
  float kl = block_sum256(klp[tid]);
  if (tid == 0) out[0] = ce / (float)N_ROWS + 0.2f * (kl / (float)N_CLS);
}

extern "C" void kernel_launch(void* const* d_in, const int* in_sizes, int n_in,
                              void* d_out, int out_size, void* d_ws, size_t ws_size,
                              hipStream_t stream) {
  const float* X          = (const float*)d_in[0];
  // d_in[1] = indices (unused by the reference loss)
  const int*   T          = (const int*)d_in[2];
  const float* proxies    = (const float*)d_in[3];
  const float* sigmas_inv = (const float*)d_in[4];

  char* ws = (char*)d_ws;
  unsigned char* Amat = (unsigned char*)ws;                            // 4 MiB
  unsigned char* Bmat = (unsigned char*)(ws + (4u << 20));             // 8 MiB
  float* tvec = (float*)(ws + (12u << 20));                            // 32 KiB
  float* klc  = (float*)(ws + (12u << 20) + (32u << 10));              // 32 KiB
  float* Pm   = (float*)(ws + (12u << 20) + (64u << 10));              // 1 MiB
  float* Psum = (float*)(ws + (13u << 20) + (64u << 10));              // 1 MiB
  float* cep  = (float*)(ws + (14u << 20) + (64u << 10));              // 1 KiB
  float* klp  = (float*)(ws + (14u << 20) + (68u << 10));              // 1 KiB
  float* out  = (float*)d_out;

  hipLaunchKernelGGL(k_prep,     dim3(N_CLS + N_ROWS), dim3(256), 0, stream,
                     proxies, sigmas_inv, X, Bmat, Amat, tvec, klc);
  hipLaunchKernelGGL(k_gemm_lse, dim3(2048),           dim3(256), 0, stream,
                     Amat, Bmat, tvec, Pm, Psum);
  hipLaunchKernelGGL(k_red,      dim3(256),            dim3(256), 0, stream,
                     Pm, Psum, Amat, Bmat, tvec, T, klc, cep, klp);
  hipLaunchKernelGGL(k_fin2,     dim3(1),              dim3(256), 0, stream,
                     cep, klp, out);
}